// Round 11
// baseline (287.000 us; speedup 1.0000x reference)
//
#include <hip/hip_runtime.h>
#include <hip/hip_fp16.h>

#define NN 50000
#define NE 800000
#define D  96
#define NB_SCAN 196   // ceil(NN/256)
#define N4 (NN * D / 4)
#define CB4 ((N4 + 255) / 256)
#define WFRAG_BLKS 5  // ceil(18*64/256)

typedef unsigned int   uint32;
typedef unsigned short uint16;
typedef short  v8s __attribute__((ext_vector_type(8)));  // 8 bf16 (4 VGPRs)
typedef float  v4f __attribute__((ext_vector_type(4)));  // MFMA accumulator
typedef unsigned int v2u __attribute__((ext_vector_type(2)));
typedef unsigned int v4u __attribute__((ext_vector_type(4)));

__device__ inline uint16 f32_to_bf16(float f) {          // round-nearest-even
    uint32 u = __float_as_uint(f);
    u += 0x7FFF + ((u >> 16) & 1);
    return (uint16)(u >> 16);
}

__device__ inline float f16_val(uint32 e) {
    __half_raw h; h.x = (uint16)(e >> 16);
    return __half2float(__half(h));
}

// combine one packed bf16 pair from each U: s = 12*u1 - 40*u2 + 32*u3, repack
__device__ inline uint32 comb2(uint32 u1, uint32 u2, uint32 u3) {
    float a1 = __uint_as_float(u1 << 16), b1 = __uint_as_float(u1 & 0xFFFF0000u);
    float a2 = __uint_as_float(u2 << 16), b2 = __uint_as_float(u2 & 0xFFFF0000u);
    float a3 = __uint_as_float(u3 << 16), b3 = __uint_as_float(u3 & 0xFFFF0000u);
    float sa = 12.f * a1 - 40.f * a2 + 32.f * a3;
    float sb = 12.f * b1 - 40.f * b2 + 32.f * b3;
    return (uint32)f32_to_bf16(sa) | ((uint32)f32_to_bf16(sb) << 16);
}

// ---- fused prep: H->bf16 | zero counts | W->B-fragment layout ----
__global__ void prep(const float4* __restrict__ H, ushort4* __restrict__ Hb,
                     const float* __restrict__ W, uint16* __restrict__ Wfrag,
                     int* __restrict__ counts) {
    int b = blockIdx.x;
    int t = threadIdx.x;
    if (b < CB4) {
        int i = b * 256 + t;
        if (i < N4) {
            float4 v = H[i];
            ushort4 o;
            o.x = f32_to_bf16(v.x); o.y = f32_to_bf16(v.y);
            o.z = f32_to_bf16(v.z); o.w = f32_to_bf16(v.w);
            Hb[i] = o;
        }
    } else if (b < CB4 + NB_SCAN) {
        int i = (b - CB4) * 256 + t;
        if (i < NN) counts[i] = 0;
    } else {
        int idx = (b - CB4 - NB_SCAN) * 256 + t;   // 0..1151 = bt*64+lane
        if (idx < 18 * 64) {
            int bt = idx >> 6, lane = idx & 63;
            int nt = bt / 3, kc = bt % 3;
            int col = nt * 16 + (lane & 15);
            int kbase = kc * 32 + (lane >> 4) * 8;
            uint16 tmp[8];
            #pragma unroll
            for (int j = 0; j < 8; ++j) tmp[j] = f32_to_bf16(W[(kbase + j) * D + col]);
            uint32* dst = (uint32*)(Wfrag + ((size_t)bt * 64 + lane) * 8);
            const uint32* src = (const uint32*)tmp;
            #pragma unroll
            for (int j = 0; j < 4; ++j) dst[j] = src[j];
        }
    }
}

// ---------------- CSR build (two-phase, slot-based) ----------------
__global__ void hist_slots(const int* __restrict__ rows, int* __restrict__ counts,
                           int* __restrict__ slot) {
    int e = blockIdx.x * blockDim.x + threadIdx.x;
    if (e < NE) slot[e] = atomicAdd(&counts[rows[e]], 1);
}

__global__ void scan_p1(const int* __restrict__ counts, int* __restrict__ partials) {
    __shared__ int red[256];
    int t = threadIdx.x;
    int i = blockIdx.x * 256 + t;
    red[t] = (i < NN) ? counts[i] : 0;
    __syncthreads();
    for (int off = 128; off > 0; off >>= 1) {
        if (t < off) red[t] += red[t + off];
        __syncthreads();
    }
    if (t == 0) partials[blockIdx.x] = red[0];
}

__global__ void scan_p23(const int* __restrict__ counts, const int* __restrict__ partials,
                         int* __restrict__ row_ptr) {
    __shared__ int pp[256];
    __shared__ int sh[256];
    int t = threadIdx.x;
    pp[t] = (t < NB_SCAN) ? partials[t] : 0;
    __syncthreads();
    for (int off = 1; off < 256; off <<= 1) {
        int u = (t >= off) ? pp[t - off] : 0;
        __syncthreads();
        pp[t] += u;
        __syncthreads();
    }
    int blk_off = (blockIdx.x == 0) ? 0 : pp[blockIdx.x - 1];
    int i = blockIdx.x * 256 + t;
    int v = (i < NN) ? counts[i] : 0;
    sh[t] = v;
    __syncthreads();
    for (int off = 1; off < 256; off <<= 1) {
        int u = (t >= off) ? sh[t - off] : 0;
        __syncthreads();
        sh[t] += u;
        __syncthreads();
    }
    int excl = sh[t] - v + blk_off;
    if (i < NN) row_ptr[i] = excl;
    if (i == NN - 1) row_ptr[NN] = excl + v;
}

// edge = col (low 16) | f16(val) (high 16); p = row_ptr[row] + slot (no atomics)
__global__ void fill_edges(const int* __restrict__ rows, const int* __restrict__ cols,
                           const float* __restrict__ vals, const int* __restrict__ row_ptr,
                           const int* __restrict__ slot, uint32* __restrict__ edges) {
    int e = blockIdx.x * blockDim.x + threadIdx.x;
    if (e < NE) {
        int p = row_ptr[rows[e]] + slot[e];
        __half_raw hr = __half_raw(__float2half(vals[e]));
        edges[p] = (uint32)(cols[e] & 0xFFFF) | ((uint32)hr.x << 16);
    }
}

// ---- feature-sliced pure SpMM: Yb[:,slice] = bf16( sum val * Xb[col,slice] )
// Slice = 32 feats = 64 B (one cache line per row) -> gather operand is
// 3.2 MB, resident in each XCD's 4 MiB L2. 16 lanes per row (2 feats each,
// 4 B gather); 4 rows per wave; 16 rows per 256-block; grid = 3125 exact.
__global__ void spmm_slice(const int* __restrict__ row_ptr, const uint32* __restrict__ edges,
                           const uint16* __restrict__ Xb, uint16* __restrict__ Yb,
                           int slice) {
    int tid = threadIdx.x;
    int fl  = tid & 15;                              // feature lane
    int r   = blockIdx.x * 16 + (tid >> 4);          // exact: 3125*16 = NN
    const uint16* xs = Xb + (size_t)slice * 32 + fl * 2;

    float a0 = 0.f, a1 = 0.f;
    int s = row_ptr[r], e = row_ptr[r + 1];
    int i = s;
    for (; i + 7 < e; i += 8) {
        uint32 ee[8];
        #pragma unroll
        for (int j = 0; j < 8; ++j) ee[j] = edges[i + j];
        uint32 xx[8];
        #pragma unroll
        for (int j = 0; j < 8; ++j)
            xx[j] = *(const uint32*)(xs + (size_t)(ee[j] & 0xFFFF) * D);
        #pragma unroll
        for (int j = 0; j < 8; ++j) {
            float v = f16_val(ee[j]);
            a0 += v * __uint_as_float(xx[j] << 16);
            a1 += v * __uint_as_float(xx[j] & 0xFFFF0000u);
        }
    }
    for (; i + 3 < e; i += 4) {
        uint32 ee[4];
        #pragma unroll
        for (int j = 0; j < 4; ++j) ee[j] = edges[i + j];
        uint32 xx[4];
        #pragma unroll
        for (int j = 0; j < 4; ++j)
            xx[j] = *(const uint32*)(xs + (size_t)(ee[j] & 0xFFFF) * D);
        #pragma unroll
        for (int j = 0; j < 4; ++j) {
            float v = f16_val(ee[j]);
            a0 += v * __uint_as_float(xx[j] << 16);
            a1 += v * __uint_as_float(xx[j] & 0xFFFF0000u);
        }
    }
    for (; i < e; ++i) {
        uint32 e0 = edges[i];
        float v = f16_val(e0);
        uint32 x = *(const uint32*)(xs + (size_t)(e0 & 0xFFFF) * D);
        a0 += v * __uint_as_float(x << 16);
        a1 += v * __uint_as_float(x & 0xFFFF0000u);
    }

    uint32 o = (uint32)f32_to_bf16(a0) | ((uint32)f32_to_bf16(a1) << 16);
    // normal store: keep the written slice cached for the chained consumer
    *(uint32*)(Yb + (size_t)r * D + slice * 32 + fl * 2) = o;
}

// ---- out = (12U1-40U2+32U3) @ W + bias via MFMA; one wave per 16-row strip --
__global__ void mfma_gemm(const uint16* __restrict__ U1, const uint16* __restrict__ U2,
                          const uint16* __restrict__ U3, const uint16* __restrict__ Wfrag,
                          const float* __restrict__ bias, float* __restrict__ out) {
    int tid   = threadIdx.x;
    int lane  = tid & 63;
    int wv    = blockIdx.x * (blockDim.x >> 6) + (tid >> 6);
    int nwv   = gridDim.x * (blockDim.x >> 6);
    int col   = lane & 15;
    int quad  = lane >> 4;

    v8s wf[6][3];
    #pragma unroll
    for (int nt = 0; nt < 6; ++nt)
        #pragma unroll
        for (int kc = 0; kc < 3; ++kc)
            wf[nt][kc] = ((const v8s*)Wfrag)[(nt * 3 + kc) * 64 + lane];

    float bi[6];
    #pragma unroll
    for (int nt = 0; nt < 6; ++nt) bi[nt] = bias[nt * 16 + col];

    for (int s = wv; s < NN / 16; s += nwv) {
        int r0 = s * 16;
        size_t base = (size_t)(r0 + col) * D + quad * 8;   // in bf16 elems
        v8s a[3];
        #pragma unroll
        for (int kc = 0; kc < 3; ++kc) {
            v4u u1 = *(const v4u*)(U1 + base + kc * 32);
            v4u u2 = *(const v4u*)(U2 + base + kc * 32);
            v4u u3 = *(const v4u*)(U3 + base + kc * 32);
            v4u sres;
            #pragma unroll
            for (int j = 0; j < 4; ++j) sres[j] = comb2(u1[j], u2[j], u3[j]);
            a[kc] = __builtin_bit_cast(v8s, sres);
        }
        v4f acc[6];
        #pragma unroll
        for (int nt = 0; nt < 6; ++nt) {
            v4f c = {0.f, 0.f, 0.f, 0.f};
            c = __builtin_amdgcn_mfma_f32_16x16x32_bf16(a[0], wf[nt][0], c, 0, 0, 0);
            c = __builtin_amdgcn_mfma_f32_16x16x32_bf16(a[1], wf[nt][1], c, 0, 0, 0);
            c = __builtin_amdgcn_mfma_f32_16x16x32_bf16(a[2], wf[nt][2], c, 0, 0, 0);
            acc[nt] = c;
        }
        #pragma unroll
        for (int nt = 0; nt < 6; ++nt) {
            float* o = out + (size_t)(r0 + quad * 4) * D + nt * 16 + col;
            o[0 * D] = acc[nt][0] + bi[nt];
            o[1 * D] = acc[nt][1] + bi[nt];
            o[2 * D] = acc[nt][2] + bi[nt];
            o[3 * D] = acc[nt][3] + bi[nt];
        }
    }
}

extern "C" void kernel_launch(void* const* d_in, const int* in_sizes, int n_in,
                              void* d_out, int out_size, void* d_ws, size_t ws_size,
                              hipStream_t stream) {
    const int*   rows = (const int*)d_in[0];
    const int*   cols = (const int*)d_in[1];
    const float* vals = (const float*)d_in[2];
    const float* H    = (const float*)d_in[3];
    const float* W    = (const float*)d_in[4];
    const float* bias = (const float*)d_in[5];
    float* out = (float*)d_out;

    char* ws = (char*)d_ws;
    uint16* Hb       = (uint16*)ws;  ws += (size_t)NN * D * 2;   // 9.6 MB
    uint16* U1b      = (uint16*)ws;  ws += (size_t)NN * D * 2;
    uint16* U2b      = (uint16*)ws;  ws += (size_t)NN * D * 2;   // slot aliases here
    uint16* U3b      = (uint16*)ws;  ws += (size_t)NN * D * 2;
    uint32* edges    = (uint32*)ws;  ws += (size_t)NE * 4;       // 3.2 MB
    uint16* Wfrag    = (uint16*)ws;  ws += (size_t)18 * 64 * 8 * 2;
    int*    counts   = (int*)ws;     ws += (size_t)NN * 4;
    int*    row_ptr  = (int*)ws;     ws += (size_t)(NN + 1) * 4;
    int*    partials = (int*)ws;     ws += 256 * 4;
    int*    slot     = (int*)U2b;    // dead before spmm writes U2b

    const int eb = (NE + 255) / 256;

    prep<<<CB4 + NB_SCAN + WFRAG_BLKS, 256, 0, stream>>>(
        (const float4*)H, (ushort4*)Hb, W, Wfrag, counts);
    hist_slots<<<eb, 256, 0, stream>>>(rows, counts, slot);
    scan_p1<<<NB_SCAN, 256, 0, stream>>>(counts, partials);
    scan_p23<<<NB_SCAN, 256, 0, stream>>>(counts, partials, row_ptr);
    fill_edges<<<eb, 256, 0, stream>>>(rows, cols, vals, row_ptr, slot, edges);

    const int sb = NN / 16;   // 3125 blocks, 16 rows each (exact)

    // Slice-major chaining: each sub-kernel's gather operand is the slice the
    // previous sub-kernel just wrote (LLC-hot; 3.2 MB fits per-XCD L2).
    for (int s = 0; s < 3; ++s) {
        spmm_slice<<<sb, 256, 0, stream>>>(row_ptr, edges, Hb,  U1b, s);  // U1 = P H
        spmm_slice<<<sb, 256, 0, stream>>>(row_ptr, edges, U1b, U2b, s);  // U2 = P U1
        spmm_slice<<<sb, 256, 0, stream>>>(row_ptr, edges, U2b, U3b, s);  // U3 = P U2
    }
    // out = (12U1 - 40U2 + 32U3) @ W + bias   (= (T0+T1+T2+T3) @ W + bias)
    mfma_gemm<<<391, 256, 0, stream>>>(U1b, U2b, U3b, Wfrag, bias, out);
}

// Round 12
// 230.936 us; speedup vs baseline: 1.2428x; 1.2428x over previous
//
#include <hip/hip_runtime.h>
#include <hip/hip_fp16.h>

#define NN 50000
#define NE 800000
#define D  96
#define NB_SCAN 196   // ceil(NN/256)
#define N4 (NN * D / 4)
#define CB4 ((N4 + 255) / 256)
#define WFRAG_BLKS 5  // ceil(18*64/256)
#define EMAX (NE + 8 * NN)          // padded edge capacity (1.2M)
#define EZ4  (EMAX / 4)             // 300000 v4u words
#define EZB  ((EZ4 + 255) / 256)    // 1172

typedef unsigned int   uint32;
typedef unsigned short uint16;
typedef short  v8s __attribute__((ext_vector_type(8)));  // 8 bf16 (4 VGPRs)
typedef float  v4f __attribute__((ext_vector_type(4)));  // MFMA accumulator
typedef unsigned int v2u __attribute__((ext_vector_type(2)));
typedef unsigned int v4u __attribute__((ext_vector_type(4)));

__device__ inline uint16 f32_to_bf16(float f) {          // round-nearest-even
    uint32 u = __float_as_uint(f);
    u += 0x7FFF + ((u >> 16) & 1);
    return (uint16)(u >> 16);
}

__device__ inline void u2f(v2u u, float& a, float& b, float& c, float& d) {
    a = __uint_as_float(u.x << 16);
    b = __uint_as_float(u.x & 0xFFFF0000u);
    c = __uint_as_float(u.y << 16);
    d = __uint_as_float(u.y & 0xFFFF0000u);
}

__device__ inline float f16_val(uint32 e) {
    __half_raw h; h.x = (uint16)(e >> 16);
    return __half2float(__half(h));
}

// combine one packed bf16 pair from each U: s = 12*u1 - 40*u2 + 32*u3, repack
__device__ inline uint32 comb2(uint32 u1, uint32 u2, uint32 u3) {
    float a1 = __uint_as_float(u1 << 16), b1 = __uint_as_float(u1 & 0xFFFF0000u);
    float a2 = __uint_as_float(u2 << 16), b2 = __uint_as_float(u2 & 0xFFFF0000u);
    float a3 = __uint_as_float(u3 << 16), b3 = __uint_as_float(u3 & 0xFFFF0000u);
    float sa = 12.f * a1 - 40.f * a2 + 32.f * a3;
    float sb = 12.f * b1 - 40.f * b2 + 32.f * b3;
    return (uint32)f32_to_bf16(sa) | ((uint32)f32_to_bf16(sb) << 16);
}

// ---- fused prep: H->bf16 | zero counts | W->B-frag layout | zero edges ----
__global__ void prep(const float4* __restrict__ H, ushort4* __restrict__ Hb,
                     const float* __restrict__ W, uint16* __restrict__ Wfrag,
                     int* __restrict__ counts, v4u* __restrict__ edges4) {
    int b = blockIdx.x;
    int t = threadIdx.x;
    if (b < CB4) {
        int i = b * 256 + t;
        if (i < N4) {
            float4 v = H[i];
            ushort4 o;
            o.x = f32_to_bf16(v.x); o.y = f32_to_bf16(v.y);
            o.z = f32_to_bf16(v.z); o.w = f32_to_bf16(v.w);
            Hb[i] = o;
        }
    } else if (b < CB4 + NB_SCAN) {
        int i = (b - CB4) * 256 + t;
        if (i < NN) counts[i] = 0;
    } else if (b < CB4 + NB_SCAN + WFRAG_BLKS) {
        int idx = (b - CB4 - NB_SCAN) * 256 + t;   // 0..1151 = bt*64+lane
        if (idx < 18 * 64) {
            int bt = idx >> 6, lane = idx & 63;
            int nt = bt / 3, kc = bt % 3;
            int col = nt * 16 + (lane & 15);
            int kbase = kc * 32 + (lane >> 4) * 8;
            uint16 tmp[8];
            #pragma unroll
            for (int j = 0; j < 8; ++j) tmp[j] = f32_to_bf16(W[(kbase + j) * D + col]);
            uint32* dst = (uint32*)(Wfrag + ((size_t)bt * 64 + lane) * 8);
            const uint32* src = (const uint32*)tmp;
            #pragma unroll
            for (int j = 0; j < 4; ++j) dst[j] = src[j];
        }
    } else {
        int i = (b - CB4 - NB_SCAN - WFRAG_BLKS) * 256 + t;
        if (i < EZ4) edges4[i] = (v4u){0u, 0u, 0u, 0u};
    }
}

// ---------------- CSR build (two-phase, slot-based, 8-padded rows) ----------
__global__ void hist_slots(const int* __restrict__ rows, int* __restrict__ counts,
                           int* __restrict__ slot) {
    int e = blockIdx.x * blockDim.x + threadIdx.x;
    if (e < NE) slot[e] = atomicAdd(&counts[rows[e]], 1);
}

__global__ void scan_p1(const int* __restrict__ counts, int* __restrict__ partials) {
    __shared__ int red[256];
    int t = threadIdx.x;
    int i = blockIdx.x * 256 + t;
    red[t] = (i < NN) ? ((counts[i] + 7) & ~7) : 0;   // padded counts
    __syncthreads();
    for (int off = 128; off > 0; off >>= 1) {
        if (t < off) red[t] += red[t + off];
        __syncthreads();
    }
    if (t == 0) partials[blockIdx.x] = red[0];
}

__global__ void scan_p23(const int* __restrict__ counts, const int* __restrict__ partials,
                         int* __restrict__ row_ptr) {
    __shared__ int pp[256];
    __shared__ int sh[256];
    int t = threadIdx.x;
    pp[t] = (t < NB_SCAN) ? partials[t] : 0;
    __syncthreads();
    for (int off = 1; off < 256; off <<= 1) {
        int u = (t >= off) ? pp[t - off] : 0;
        __syncthreads();
        pp[t] += u;
        __syncthreads();
    }
    int blk_off = (blockIdx.x == 0) ? 0 : pp[blockIdx.x - 1];
    int i = blockIdx.x * 256 + t;
    int v = (i < NN) ? ((counts[i] + 7) & ~7) : 0;    // padded counts
    sh[t] = v;
    __syncthreads();
    for (int off = 1; off < 256; off <<= 1) {
        int u = (t >= off) ? sh[t - off] : 0;
        __syncthreads();
        sh[t] += u;
        __syncthreads();
    }
    int excl = sh[t] - v + blk_off;
    if (i < NN) row_ptr[i] = excl;
    if (i == NN - 1) row_ptr[NN] = excl + v;
}

// edge = col (low 16) | f16(val) (high 16); p = row_ptr[row] + slot (no atomics)
__global__ void fill_edges(const int* __restrict__ rows, const int* __restrict__ cols,
                           const float* __restrict__ vals, const int* __restrict__ row_ptr,
                           const int* __restrict__ slot, uint32* __restrict__ edges) {
    int e = blockIdx.x * blockDim.x + threadIdx.x;
    if (e < NE) {
        int p = row_ptr[rows[e]] + slot[e];
        __half_raw hr = __half_raw(__float2half(vals[e]));
        edges[p] = (uint32)(cols[e] & 0xFFFF) | ((uint32)hr.x << 16);
    }
}

// ---- pure SpMM: Yb = bf16( sum val * Xb[col] ). Rows padded to 8 edges
// (pads are val=0,col=0 -> contribute 0), so the loop is tail-free and the
// 8 edge words load as two dwordx4. 32 lanes/row, lanes 0..23 own 4 feats.
__global__ void spmm(const int* __restrict__ row_ptr, const uint32* __restrict__ edges,
                     const uint16* __restrict__ Xb, uint16* __restrict__ Yb) {
    int tid  = threadIdx.x;
    int lane = tid & 31;
    int g    = tid >> 5;
    int r = blockIdx.x * 8 + g;
    if (r >= NN) return;
    if (lane >= 24) return;                       // exec-masked idle lanes

    const v2u* xbase = (const v2u*)Xb;            // row stride = 24 v2u

    float ax = 0.f, ay = 0.f, az = 0.f, aw = 0.f;
    int s = row_ptr[r];
    int e = row_ptr[r + 1];
    for (int i = s; i < e; i += 8) {
        v4u ea = *(const v4u*)(edges + i);        // 32 B aligned (i % 8 == 0)
        v4u eb = *(const v4u*)(edges + i + 4);
        uint32 ee[8] = {ea.x, ea.y, ea.z, ea.w, eb.x, eb.y, eb.z, eb.w};
        v2u xx[8];
        #pragma unroll
        for (int j = 0; j < 8; ++j)
            xx[j] = xbase[(size_t)(ee[j] & 0xFFFF) * 24 + lane];
        #pragma unroll
        for (int j = 0; j < 8; ++j) {
            float v = f16_val(ee[j]);
            float x0,x1,x2,x3;
            u2f(xx[j], x0,x1,x2,x3);
            ax += v*x0; ay += v*x1; az += v*x2; aw += v*x3;
        }
    }

    v2u o;
    o.x = (uint32)f32_to_bf16(ax) | ((uint32)f32_to_bf16(ay) << 16);
    o.y = (uint32)f32_to_bf16(az) | ((uint32)f32_to_bf16(aw) << 16);
    __builtin_nontemporal_store(o, (v2u*)(Yb + (size_t)r * D) + lane);
}

// ---- out = (12U1-40U2+32U3) @ W + bias via MFMA; one wave per 16-row strip --
__global__ void mfma_gemm(const uint16* __restrict__ U1, const uint16* __restrict__ U2,
                          const uint16* __restrict__ U3, const uint16* __restrict__ Wfrag,
                          const float* __restrict__ bias, float* __restrict__ out) {
    int tid   = threadIdx.x;
    int lane  = tid & 63;
    int wv    = blockIdx.x * (blockDim.x >> 6) + (tid >> 6);
    int nwv   = gridDim.x * (blockDim.x >> 6);
    int col   = lane & 15;
    int quad  = lane >> 4;

    v8s wf[6][3];
    #pragma unroll
    for (int nt = 0; nt < 6; ++nt)
        #pragma unroll
        for (int kc = 0; kc < 3; ++kc)
            wf[nt][kc] = ((const v8s*)Wfrag)[(nt * 3 + kc) * 64 + lane];

    float bi[6];
    #pragma unroll
    for (int nt = 0; nt < 6; ++nt) bi[nt] = bias[nt * 16 + col];

    for (int s = wv; s < NN / 16; s += nwv) {
        int r0 = s * 16;
        size_t base = (size_t)(r0 + col) * D + quad * 8;   // in bf16 elems
        v8s a[3];
        #pragma unroll
        for (int kc = 0; kc < 3; ++kc) {
            v4u u1 = *(const v4u*)(U1 + base + kc * 32);
            v4u u2 = *(const v4u*)(U2 + base + kc * 32);
            v4u u3 = *(const v4u*)(U3 + base + kc * 32);
            v4u sres;
            #pragma unroll
            for (int j = 0; j < 4; ++j) sres[j] = comb2(u1[j], u2[j], u3[j]);
            a[kc] = __builtin_bit_cast(v8s, sres);
        }
        v4f acc[6];
        #pragma unroll
        for (int nt = 0; nt < 6; ++nt) {
            v4f c = {0.f, 0.f, 0.f, 0.f};
            c = __builtin_amdgcn_mfma_f32_16x16x32_bf16(a[0], wf[nt][0], c, 0, 0, 0);
            c = __builtin_amdgcn_mfma_f32_16x16x32_bf16(a[1], wf[nt][1], c, 0, 0, 0);
            c = __builtin_amdgcn_mfma_f32_16x16x32_bf16(a[2], wf[nt][2], c, 0, 0, 0);
            acc[nt] = c;
        }
        #pragma unroll
        for (int nt = 0; nt < 6; ++nt) {
            float* o = out + (size_t)(r0 + quad * 4) * D + nt * 16 + col;
            __builtin_nontemporal_store(acc[nt][0] + bi[nt], o + 0 * D);
            __builtin_nontemporal_store(acc[nt][1] + bi[nt], o + 1 * D);
            __builtin_nontemporal_store(acc[nt][2] + bi[nt], o + 2 * D);
            __builtin_nontemporal_store(acc[nt][3] + bi[nt], o + 3 * D);
        }
    }
}

extern "C" void kernel_launch(void* const* d_in, const int* in_sizes, int n_in,
                              void* d_out, int out_size, void* d_ws, size_t ws_size,
                              hipStream_t stream) {
    const int*   rows = (const int*)d_in[0];
    const int*   cols = (const int*)d_in[1];
    const float* vals = (const float*)d_in[2];
    const float* H    = (const float*)d_in[3];
    const float* W    = (const float*)d_in[4];
    const float* bias = (const float*)d_in[5];
    float* out = (float*)d_out;

    char* ws = (char*)d_ws;
    uint16* Hb       = (uint16*)ws;  ws += (size_t)NN * D * 2;   // 9.6 MB
    uint16* U1b      = (uint16*)ws;  ws += (size_t)NN * D * 2;
    uint16* U2b      = (uint16*)ws;  ws += (size_t)NN * D * 2;   // slot aliases here
    uint16* U3b      = (uint16*)ws;  ws += (size_t)NN * D * 2;
    uint32* edges    = (uint32*)ws;  ws += (size_t)EMAX * 4;     // 4.8 MB padded
    uint16* Wfrag    = (uint16*)ws;  ws += (size_t)18 * 64 * 8 * 2;
    int*    counts   = (int*)ws;     ws += (size_t)NN * 4;
    int*    row_ptr  = (int*)ws;     ws += (size_t)(NN + 1) * 4;
    int*    partials = (int*)ws;     ws += 256 * 4;
    int*    slot     = (int*)U2b;    // dead before spmm writes U2b

    const int eb = (NE + 255) / 256;

    prep<<<CB4 + NB_SCAN + WFRAG_BLKS + EZB, 256, 0, stream>>>(
        (const float4*)H, (ushort4*)Hb, W, Wfrag, counts, (v4u*)edges);
    hist_slots<<<eb, 256, 0, stream>>>(rows, counts, slot);
    scan_p1<<<NB_SCAN, 256, 0, stream>>>(counts, partials);
    scan_p23<<<NB_SCAN, 256, 0, stream>>>(counts, partials, row_ptr);
    fill_edges<<<eb, 256, 0, stream>>>(rows, cols, vals, row_ptr, slot, edges);

    const int sb = (NN + 7) / 8;   // 6250 blocks, 8 rows each

    // U1 = P H,  U2 = P U1,  U3 = P U2   (pure monomials)
    spmm<<<sb, 256, 0, stream>>>(row_ptr, edges, Hb,  U1b);
    spmm<<<sb, 256, 0, stream>>>(row_ptr, edges, U1b, U2b);
    spmm<<<sb, 256, 0, stream>>>(row_ptr, edges, U2b, U3b);
    // out = (12U1 - 40U2 + 32U3) @ W + bias   (= (T0+T1+T2+T3) @ W + bias)
    mfma_gemm<<<782, 256, 0, stream>>>(U1b, U2b, U3b, Wfrag, bias, out);
}

// Round 13
// 229.931 us; speedup vs baseline: 1.2482x; 1.0044x over previous
//
#include <hip/hip_runtime.h>
#include <hip/hip_fp16.h>

#define NN 50000
#define NE 800000
#define D  96
#define NB_SCAN 196   // ceil(NN/256)
#define N4 (NN * D / 4)
#define CB4 ((N4 + 255) / 256)
#define WFRAG_BLKS 5  // ceil(18*64/256)
#define EMAX (NE + 8 * NN)          // padded edge capacity (1.2M)
#define EZ4  (EMAX / 4)             // 300000 v4u words
#define EZB  ((EZ4 + 255) / 256)    // 1172

typedef unsigned int   uint32;
typedef unsigned short uint16;
typedef short  v8s __attribute__((ext_vector_type(8)));  // 8 bf16 (4 VGPRs)
typedef float  v4f __attribute__((ext_vector_type(4)));  // MFMA accumulator
typedef unsigned int v2u __attribute__((ext_vector_type(2)));
typedef unsigned int v4u __attribute__((ext_vector_type(4)));
typedef float v2f __attribute__((ext_vector_type(2)));

__device__ inline uint16 f32_to_bf16(float f) {          // round-nearest-even
    uint32 u = __float_as_uint(f);
    u += 0x7FFF + ((u >> 16) & 1);
    return (uint16)(u >> 16);
}

__device__ inline void u2f(v2u u, float& a, float& b, float& c, float& d) {
    a = __uint_as_float(u.x << 16);
    b = __uint_as_float(u.x & 0xFFFF0000u);
    c = __uint_as_float(u.y << 16);
    d = __uint_as_float(u.y & 0xFFFF0000u);
}

__device__ inline float f16_val(uint32 e) {
    __half_raw h; h.x = (uint16)(e >> 16);
    return __half2float(__half(h));
}

// ---- fused prep: H->bf16 | zero counts | W->B-frag layout | zero edges ----
__global__ void prep(const float4* __restrict__ H, ushort4* __restrict__ Hb,
                     const float* __restrict__ W, uint16* __restrict__ Wfrag,
                     int* __restrict__ counts, v4u* __restrict__ edges4) {
    int b = blockIdx.x;
    int t = threadIdx.x;
    if (b < CB4) {
        int i = b * 256 + t;
        if (i < N4) {
            float4 v = H[i];
            ushort4 o;
            o.x = f32_to_bf16(v.x); o.y = f32_to_bf16(v.y);
            o.z = f32_to_bf16(v.z); o.w = f32_to_bf16(v.w);
            Hb[i] = o;
        }
    } else if (b < CB4 + NB_SCAN) {
        int i = (b - CB4) * 256 + t;
        if (i < NN) counts[i] = 0;
    } else if (b < CB4 + NB_SCAN + WFRAG_BLKS) {
        int idx = (b - CB4 - NB_SCAN) * 256 + t;   // 0..1151 = bt*64+lane
        if (idx < 18 * 64) {
            int bt = idx >> 6, lane = idx & 63;
            int nt = bt / 3, kc = bt % 3;
            int col = nt * 16 + (lane & 15);
            int kbase = kc * 32 + (lane >> 4) * 8;
            uint16 tmp[8];
            #pragma unroll
            for (int j = 0; j < 8; ++j) tmp[j] = f32_to_bf16(W[(kbase + j) * D + col]);
            uint32* dst = (uint32*)(Wfrag + ((size_t)bt * 64 + lane) * 8);
            const uint32* src = (const uint32*)tmp;
            #pragma unroll
            for (int j = 0; j < 4; ++j) dst[j] = src[j];
        }
    } else {
        int i = (b - CB4 - NB_SCAN - WFRAG_BLKS) * 256 + t;
        if (i < EZ4) edges4[i] = (v4u){0u, 0u, 0u, 0u};
    }
}

// ---------------- CSR build (two-phase, slot-based, 8-padded rows) ----------
// 2 edges per thread.
__global__ void hist_slots(const int* __restrict__ rows, int* __restrict__ counts,
                           int* __restrict__ slot) {
    int base = (blockIdx.x * blockDim.x + threadIdx.x) * 2;
    if (base < NE) {
        v2u rr = *(const v2u*)(rows + base);
        slot[base]     = atomicAdd(&counts[rr.x], 1);
        slot[base + 1] = atomicAdd(&counts[rr.y], 1);
    }
}

__global__ void scan_p1(const int* __restrict__ counts, int* __restrict__ partials) {
    __shared__ int red[256];
    int t = threadIdx.x;
    int i = blockIdx.x * 256 + t;
    red[t] = (i < NN) ? ((counts[i] + 7) & ~7) : 0;   // padded counts
    __syncthreads();
    for (int off = 128; off > 0; off >>= 1) {
        if (t < off) red[t] += red[t + off];
        __syncthreads();
    }
    if (t == 0) partials[blockIdx.x] = red[0];
}

__global__ void scan_p23(const int* __restrict__ counts, const int* __restrict__ partials,
                         int* __restrict__ row_ptr) {
    __shared__ int pp[256];
    __shared__ int sh[256];
    int t = threadIdx.x;
    pp[t] = (t < NB_SCAN) ? partials[t] : 0;
    __syncthreads();
    for (int off = 1; off < 256; off <<= 1) {
        int u = (t >= off) ? pp[t - off] : 0;
        __syncthreads();
        pp[t] += u;
        __syncthreads();
    }
    int blk_off = (blockIdx.x == 0) ? 0 : pp[blockIdx.x - 1];
    int i = blockIdx.x * 256 + t;
    int v = (i < NN) ? ((counts[i] + 7) & ~7) : 0;    // padded counts
    sh[t] = v;
    __syncthreads();
    for (int off = 1; off < 256; off <<= 1) {
        int u = (t >= off) ? sh[t - off] : 0;
        __syncthreads();
        sh[t] += u;
        __syncthreads();
    }
    int excl = sh[t] - v + blk_off;
    if (i < NN) row_ptr[i] = excl;
    if (i == NN - 1) row_ptr[NN] = excl + v;
}

// edge = col (low 16) | f16(val) (high 16); p = row_ptr[row] + slot. 2/thread.
__global__ void fill_edges(const int* __restrict__ rows, const int* __restrict__ cols,
                           const float* __restrict__ vals, const int* __restrict__ row_ptr,
                           const int* __restrict__ slot, uint32* __restrict__ edges) {
    int base = (blockIdx.x * blockDim.x + threadIdx.x) * 2;
    if (base < NE) {
        v2u rr = *(const v2u*)(rows + base);
        v2u cc = *(const v2u*)(cols + base);
        v2f vv = *(const v2f*)(vals + base);
        v2u ss = *(const v2u*)(slot + base);
        __half_raw h0 = __half_raw(__float2half(vv.x));
        __half_raw h1 = __half_raw(__float2half(vv.y));
        edges[row_ptr[rr.x] + ss.x] = (cc.x & 0xFFFF) | ((uint32)h0.x << 16);
        edges[row_ptr[rr.y] + ss.y] = (cc.y & 0xFFFF) | ((uint32)h1.x << 16);
    }
}

// ---- pure SpMM: Yb = bf16( sum val * Xb[col] ). Rows padded to 8 edges;
// main loop unrolled x16 (16 gathers in flight), 8-tail. 32 lanes/row,
// lanes 0..23 own 4 feats (8 B gathers).
__global__ void spmm(const int* __restrict__ row_ptr, const uint32* __restrict__ edges,
                     const uint16* __restrict__ Xb, uint16* __restrict__ Yb) {
    int tid  = threadIdx.x;
    int lane = tid & 31;
    int g    = tid >> 5;
    int r = blockIdx.x * 8 + g;
    if (r >= NN) return;
    if (lane >= 24) return;

    const v2u* xbase = (const v2u*)Xb;            // row stride = 24 v2u

    float ax = 0.f, ay = 0.f, az = 0.f, aw = 0.f;
    int s = row_ptr[r];
    int e = row_ptr[r + 1];
    int i = s;
    for (; i + 15 < e; i += 16) {
        v4u e0 = *(const v4u*)(edges + i);
        v4u e1 = *(const v4u*)(edges + i + 4);
        v4u e2 = *(const v4u*)(edges + i + 8);
        v4u e3 = *(const v4u*)(edges + i + 12);
        uint32 ee[16] = {e0.x,e0.y,e0.z,e0.w, e1.x,e1.y,e1.z,e1.w,
                         e2.x,e2.y,e2.z,e2.w, e3.x,e3.y,e3.z,e3.w};
        v2u xx[16];
        #pragma unroll
        for (int j = 0; j < 16; ++j)
            xx[j] = xbase[(size_t)(ee[j] & 0xFFFF) * 24 + lane];
        #pragma unroll
        for (int j = 0; j < 16; ++j) {
            float v = f16_val(ee[j]);
            float x0,x1,x2,x3;
            u2f(xx[j], x0,x1,x2,x3);
            ax += v*x0; ay += v*x1; az += v*x2; aw += v*x3;
        }
    }
    for (; i < e; i += 8) {
        v4u ea = *(const v4u*)(edges + i);
        v4u eb = *(const v4u*)(edges + i + 4);
        uint32 ee[8] = {ea.x, ea.y, ea.z, ea.w, eb.x, eb.y, eb.z, eb.w};
        v2u xx[8];
        #pragma unroll
        for (int j = 0; j < 8; ++j)
            xx[j] = xbase[(size_t)(ee[j] & 0xFFFF) * 24 + lane];
        #pragma unroll
        for (int j = 0; j < 8; ++j) {
            float v = f16_val(ee[j]);
            float x0,x1,x2,x3;
            u2f(xx[j], x0,x1,x2,x3);
            ax += v*x0; ay += v*x1; az += v*x2; aw += v*x3;
        }
    }

    v2u o;
    o.x = (uint32)f32_to_bf16(ax) | ((uint32)f32_to_bf16(ay) << 16);
    o.y = (uint32)f32_to_bf16(az) | ((uint32)f32_to_bf16(aw) << 16);
    __builtin_nontemporal_store(o, (v2u*)(Yb + (size_t)r * D) + lane);
}

// ---- fused pass 3: Sb = bf16( 12*U1 - 40*U2 + 32 * P U2 ) ------------------
__global__ void spmm_fuse(const int* __restrict__ row_ptr, const uint32* __restrict__ edges,
                          const uint16* __restrict__ U1, const uint16* __restrict__ U2,
                          uint16* __restrict__ Sb) {
    int tid  = threadIdx.x;
    int lane = tid & 31;
    int g    = tid >> 5;
    int r = blockIdx.x * 8 + g;
    if (r >= NN) return;
    if (lane >= 24) return;

    const v2u* xbase = (const v2u*)U2;            // gather operand = U2

    float ax = 0.f, ay = 0.f, az = 0.f, aw = 0.f;
    int s = row_ptr[r];
    int e = row_ptr[r + 1];
    int i = s;
    for (; i + 15 < e; i += 16) {
        v4u e0 = *(const v4u*)(edges + i);
        v4u e1 = *(const v4u*)(edges + i + 4);
        v4u e2 = *(const v4u*)(edges + i + 8);
        v4u e3 = *(const v4u*)(edges + i + 12);
        uint32 ee[16] = {e0.x,e0.y,e0.z,e0.w, e1.x,e1.y,e1.z,e1.w,
                         e2.x,e2.y,e2.z,e2.w, e3.x,e3.y,e3.z,e3.w};
        v2u xx[16];
        #pragma unroll
        for (int j = 0; j < 16; ++j)
            xx[j] = xbase[(size_t)(ee[j] & 0xFFFF) * 24 + lane];
        #pragma unroll
        for (int j = 0; j < 16; ++j) {
            float v = f16_val(ee[j]);
            float x0,x1,x2,x3;
            u2f(xx[j], x0,x1,x2,x3);
            ax += v*x0; ay += v*x1; az += v*x2; aw += v*x3;
        }
    }
    for (; i < e; i += 8) {
        v4u ea = *(const v4u*)(edges + i);
        v4u eb = *(const v4u*)(edges + i + 4);
        uint32 ee[8] = {ea.x, ea.y, ea.z, ea.w, eb.x, eb.y, eb.z, eb.w};
        v2u xx[8];
        #pragma unroll
        for (int j = 0; j < 8; ++j)
            xx[j] = xbase[(size_t)(ee[j] & 0xFFFF) * 24 + lane];
        #pragma unroll
        for (int j = 0; j < 8; ++j) {
            float v = f16_val(ee[j]);
            float x0,x1,x2,x3;
            u2f(xx[j], x0,x1,x2,x3);
            ax += v*x0; ay += v*x1; az += v*x2; aw += v*x3;
        }
    }

    v2u u1 = __builtin_nontemporal_load((const v2u*)(U1 + (size_t)r * D) + lane);
    v2u u2 = xbase[(size_t)r * 24 + lane];
    float p0,p1,p2,p3, q0,q1,q2,q3;
    u2f(u1, p0,p1,p2,p3);
    u2f(u2, q0,q1,q2,q3);
    float s0 = 12.f*p0 - 40.f*q0 + 32.f*ax;
    float s1 = 12.f*p1 - 40.f*q1 + 32.f*ay;
    float s2 = 12.f*p2 - 40.f*q2 + 32.f*az;
    float s3 = 12.f*p3 - 40.f*q3 + 32.f*aw;

    v2u o;
    o.x = (uint32)f32_to_bf16(s0) | ((uint32)f32_to_bf16(s1) << 16);
    o.y = (uint32)f32_to_bf16(s2) | ((uint32)f32_to_bf16(s3) << 16);
    __builtin_nontemporal_store(o, (v2u*)(Sb + (size_t)r * D) + lane);
}

// ---- out = Sb @ W + bias via MFMA; one wave per 16-row strip (grid-stride) --
__global__ void mfma_gemm(const uint16* __restrict__ Sb, const uint16* __restrict__ Wfrag,
                          const float* __restrict__ bias, float* __restrict__ out) {
    int tid   = threadIdx.x;
    int lane  = tid & 63;
    int wv    = blockIdx.x * (blockDim.x >> 6) + (tid >> 6);
    int nwv   = gridDim.x * (blockDim.x >> 6);
    int col   = lane & 15;
    int quad  = lane >> 4;

    v8s wf[6][3];
    #pragma unroll
    for (int nt = 0; nt < 6; ++nt)
        #pragma unroll
        for (int kc = 0; kc < 3; ++kc)
            wf[nt][kc] = ((const v8s*)Wfrag)[(nt * 3 + kc) * 64 + lane];

    float bi[6];
    #pragma unroll
    for (int nt = 0; nt < 6; ++nt) bi[nt] = bias[nt * 16 + col];

    for (int s = wv; s < NN / 16; s += nwv) {
        int r0 = s * 16;
        const uint16* arow = Sb + (size_t)(r0 + col) * D + quad * 8;
        v8s a0 = *((const v8s*)(arow));
        v8s a1 = *((const v8s*)(arow + 32));
        v8s a2 = *((const v8s*)(arow + 64));
        v4f acc[6];
        #pragma unroll
        for (int nt = 0; nt < 6; ++nt) {
            v4f c = {0.f, 0.f, 0.f, 0.f};
            c = __builtin_amdgcn_mfma_f32_16x16x32_bf16(a0, wf[nt][0], c, 0, 0, 0);
            c = __builtin_amdgcn_mfma_f32_16x16x32_bf16(a1, wf[nt][1], c, 0, 0, 0);
            c = __builtin_amdgcn_mfma_f32_16x16x32_bf16(a2, wf[nt][2], c, 0, 0, 0);
            acc[nt] = c;
        }
        #pragma unroll
        for (int nt = 0; nt < 6; ++nt) {
            float* o = out + (size_t)(r0 + quad * 4) * D + nt * 16 + col;
            __builtin_nontemporal_store(acc[nt][0] + bi[nt], o + 0 * D);
            __builtin_nontemporal_store(acc[nt][1] + bi[nt], o + 1 * D);
            __builtin_nontemporal_store(acc[nt][2] + bi[nt], o + 2 * D);
            __builtin_nontemporal_store(acc[nt][3] + bi[nt], o + 3 * D);
        }
    }
}

extern "C" void kernel_launch(void* const* d_in, const int* in_sizes, int n_in,
                              void* d_out, int out_size, void* d_ws, size_t ws_size,
                              hipStream_t stream) {
    const int*   rows = (const int*)d_in[0];
    const int*   cols = (const int*)d_in[1];
    const float* vals = (const float*)d_in[2];
    const float* H    = (const float*)d_in[3];
    const float* W    = (const float*)d_in[4];
    const float* bias = (const float*)d_in[5];
    float* out = (float*)d_out;

    char* ws = (char*)d_ws;
    uint16* Hb       = (uint16*)ws;  ws += (size_t)NN * D * 2;   // 9.6 MB
    uint16* U1b      = (uint16*)ws;  ws += (size_t)NN * D * 2;
    uint16* U2b      = (uint16*)ws;  ws += (size_t)NN * D * 2;   // slot aliases here
    uint16* Sb       = (uint16*)ws;  ws += (size_t)NN * D * 2;
    uint32* edges    = (uint32*)ws;  ws += (size_t)EMAX * 4;     // 4.8 MB padded
    uint16* Wfrag    = (uint16*)ws;  ws += (size_t)18 * 64 * 8 * 2;
    int*    counts   = (int*)ws;     ws += (size_t)NN * 4;
    int*    row_ptr  = (int*)ws;     ws += (size_t)(NN + 1) * 4;
    int*    partials = (int*)ws;     ws += 256 * 4;
    int*    slot     = (int*)U2b;    // dead before spmm writes U2b

    const int eb2 = (NE / 2 + 255) / 256;   // 2 edges/thread

    prep<<<CB4 + NB_SCAN + WFRAG_BLKS + EZB, 256, 0, stream>>>(
        (const float4*)H, (ushort4*)Hb, W, Wfrag, counts, (v4u*)edges);
    hist_slots<<<eb2, 256, 0, stream>>>(rows, counts, slot);
    scan_p1<<<NB_SCAN, 256, 0, stream>>>(counts, partials);
    scan_p23<<<NB_SCAN, 256, 0, stream>>>(counts, partials, row_ptr);
    fill_edges<<<eb2, 256, 0, stream>>>(rows, cols, vals, row_ptr, slot, edges);

    const int sb = (NN + 7) / 8;   // 6250 blocks, 8 rows each

    // U1 = P H,  U2 = P U1,  Sb = 12U1 - 40U2 + 32 P U2  (= T0+T1+T2+T3)
    spmm<<<sb, 256, 0, stream>>>(row_ptr, edges, Hb,  U1b);
    spmm<<<sb, 256, 0, stream>>>(row_ptr, edges, U1b, U2b);
    spmm_fuse<<<sb, 256, 0, stream>>>(row_ptr, edges, U1b, U2b, Sb);
    // out = Sb @ W + bias
    mfma_gemm<<<782, 256, 0, stream>>>(Sb, Wfrag, bias, out);
}